// Round 1
// baseline (251.138 us; speedup 1.0000x reference)
//
#include <hip/hip_runtime.h>

#define EMBED 768
#define NH 12
#define HD 64
#define MEMN 64
#define BB 8
#define TT 1024
#define ROWS 8192
#define QKV_N 2304
#define QSZ 6291456           // B*T*C = B*NH*TT*HD (elements)

typedef short bf16x8_t __attribute__((ext_vector_type(8)));
typedef float f32x4_t __attribute__((ext_vector_type(4)));

__device__ __forceinline__ unsigned short f2b(float f){
    union { float f; unsigned int i; } v; v.f = f;
    unsigned int x = v.i;
    unsigned int r = x + 0x7fffu + ((x >> 16) & 1u);
    return (unsigned short)(r >> 16);
}
// round-half-up convert for non-negative values (softmax p)
__device__ __forceinline__ unsigned short f2b_ru(float f){
    union { float f; unsigned int i; } v; v.f = f;
    return (unsigned short)((v.i + 0x8000u) >> 16);
}

// async global->LDS, 16B per lane; lds base must be wave-uniform (lane*16 implicit)
__device__ __forceinline__ void gl16(const unsigned short* g, unsigned short* l){
    __builtin_amdgcn_global_load_lds(
        (const __attribute__((address_space(1))) void*)g,
        (__attribute__((address_space(3))) void*)l,
        16, 0, 0);
}

// ---- fused prep: x cvt + w_qkv tcvt + w_out tcvt + memproj (one graph node) ----
#define PREP_CVT   3072
#define PREP_TQKV  4800
#define PREP_TOUT  5376
#define PREP_TOTAL 5388

__global__ __launch_bounds__(256) void prep_kernel(
    const float* __restrict__ x,
    const float* __restrict__ w_qkv,
    const float* __restrict__ w_out,
    const float* __restrict__ memory,
    const float* __restrict__ w_mem,
    const float* __restrict__ b_mem,
    unsigned short* __restrict__ xb,
    unsigned short* __restrict__ wqkvT,
    unsigned short* __restrict__ woutT,
    unsigned short* __restrict__ mem_k,
    unsigned short* __restrict__ mem_v)
{
    __shared__ unsigned short pool[5120];
    const int bid = blockIdx.x;
    const int t = threadIdx.x;

    if (bid < PREP_CVT) {
        int i = bid * 2048 + t * 8;
        float4 f0 = *(const float4*)&x[i];
        float4 f1 = *(const float4*)&x[i + 4];
        union { bf16x8_t v; unsigned short s[8]; } u;
        u.s[0] = f2b(f0.x); u.s[1] = f2b(f0.y); u.s[2] = f2b(f0.z); u.s[3] = f2b(f0.w);
        u.s[4] = f2b(f1.x); u.s[5] = f2b(f1.y); u.s[6] = f2b(f1.z); u.s[7] = f2b(f1.w);
        *(bf16x8_t*)&xb[i] = u.v;
    } else if (bid < PREP_TOUT) {
        const float* in; unsigned short* out; int R, C, loc;
        if (bid < PREP_TQKV) { in = w_qkv; out = wqkvT; R = EMBED; C = QKV_N; loc = bid - PREP_CVT; }
        else                 { in = w_out; out = woutT; R = EMBED; C = EMBED; loc = bid - PREP_TQKV; }
        int nbc = C / 32;
        int bc = (loc % nbc) * 32, br = (loc / nbc) * 32;
        unsigned short (*tile)[33] = (unsigned short(*)[33])pool;
        int lr = t >> 5, lc = t & 31;
        for (int i = 0; i < 4; i++) {
            int r = lr + i * 8;
            tile[r][lc] = f2b(in[(size_t)(br + r) * C + bc + lc]);
        }
        __syncthreads();
        for (int i = 0; i < 4; i++) {
            int r = lr + i * 8;
            out[(size_t)(bc + r) * R + br + lc] = tile[lc][r];
        }
    } else {
        unsigned short (*As)[40] = (unsigned short(*)[40])pool;
        unsigned short (*Bs)[40] = (unsigned short(*)[40])(pool + 2560);
        int wave = t >> 6, lane = t & 63;
        int ln = lane & 15, lq = lane >> 4;
        int bn = (bid - PREP_TOUT) * 64;
        const int K = EMBED, N = EMBED;

        f32x4_t acc[4];
        for (int i = 0; i < 4; i++) acc[i] = (f32x4_t)(0.f);
        int sm = t >> 2, sk = (t & 3) * 8;
        int bk = t >> 3, bn8 = (t & 7) * 8;

        for (int k0 = 0; k0 < K; k0 += 32) {
            __syncthreads();
            {
                float4 f0 = *(const float4*)&memory[(size_t)sm * K + k0 + sk];
                float4 f1 = *(const float4*)&memory[(size_t)sm * K + k0 + sk + 4];
                unsigned short* ap = &As[sm][sk];
                ap[0] = f2b(f0.x); ap[1] = f2b(f0.y); ap[2] = f2b(f0.z); ap[3] = f2b(f0.w);
                ap[4] = f2b(f1.x); ap[5] = f2b(f1.y); ap[6] = f2b(f1.z); ap[7] = f2b(f1.w);
            }
            {
                float4 g0 = *(const float4*)&w_mem[(size_t)(k0 + bk) * N + bn + bn8];
                float4 g1 = *(const float4*)&w_mem[(size_t)(k0 + bk) * N + bn + bn8 + 4];
                Bs[bn8 + 0][bk] = f2b(g0.x); Bs[bn8 + 1][bk] = f2b(g0.y);
                Bs[bn8 + 2][bk] = f2b(g0.z); Bs[bn8 + 3][bk] = f2b(g0.w);
                Bs[bn8 + 4][bk] = f2b(g1.x); Bs[bn8 + 5][bk] = f2b(g1.y);
                Bs[bn8 + 6][bk] = f2b(g1.z); Bs[bn8 + 7][bk] = f2b(g1.w);
            }
            __syncthreads();
            bf16x8_t a = *(bf16x8_t*)&As[wave * 16 + ln][lq * 8];
            for (int nt = 0; nt < 4; nt++) {
                bf16x8_t bf = *(bf16x8_t*)&Bs[nt * 16 + ln][lq * 8];
                acc[nt] = __builtin_amdgcn_mfma_f32_16x16x32_bf16(a, bf, acc[nt], 0, 0, 0);
            }
        }
        for (int nt = 0; nt < 4; nt++) {
            int c = bn + nt * 16 + ln;
            float bv = b_mem[c];
            for (int r = 0; r < 4; r++) {
                int row = wave * 16 + lq * 4 + r;
                int h = c >> 6, d = c & 63;
                unsigned short o = f2b(acc[nt][r] + bv);
                mem_k[((h * 64 + row) << 6) + d] = o;   // [H,M,D]
                mem_v[((h * 64 + d) << 6) + row] = o;   // [H,D,M]
            }
        }
    }
}

// ---- bf16 [BH][T][D] -> [BH][D][T] transpose, coalesced both sides ----
__global__ __launch_bounds__(256) void vtrans_kernel(
    const unsigned short* __restrict__ in, unsigned short* __restrict__ out)
{
    __shared__ unsigned short tile[64][72];
    int t0 = blockIdx.x * 64;
    int bh = blockIdx.y;
    const unsigned short* ip = in + ((size_t)bh * TT + t0) * 64;
    unsigned short* op = out + ((size_t)bh * 64) * TT + t0;
    int t = threadIdx.x;
    for (int i = 0; i < 2; i++) {
        int idx = i * 256 + t;
        int r = idx >> 3, c8 = (idx & 7) * 8;
        *(bf16x8_t*)&tile[r][c8] = *(const bf16x8_t*)&ip[(size_t)r * 64 + c8];
    }
    __syncthreads();
    for (int i = 0; i < 2; i++) {
        int idx = i * 256 + t;
        int d = idx >> 3, tc8 = (idx & 7) * 8;
        union { bf16x8_t v; unsigned short s[8]; } u;
        for (int j = 0; j < 8; j++) u.s[j] = tile[tc8 + j][d];
        *(bf16x8_t*)&op[(size_t)d * TT + tc8] = u.v;
    }
}

// ---- 256x128 bf16 GEMM, 512 threads (8 waves x 64x64 quadrant), BK=64,
// XOR-swizzled LDS. r11: double-buffered 2-phase pipeline (T3 minimum recipe):
// stage k+1 into buf^1 BEFORE computing buf, one __syncthreads per step whose
// implicit vmcnt(0) drain now overlaps the 32-MFMA phase instead of stalling
// cold (old shape exposed the full load round-trip serially 12x -> MfmaUtil 18%).
// LDS 96KB -> 1 block/CU; pipeline replaces TLP for latency hiding.
// XCD swizzle: 576 blocks = 8 x 72; each XCD owns a contiguous 4x18 chunk of
// the tile grid so the 18 N-tiles sharing an A-panel hit the same L2. ----
__global__ __launch_bounds__(512) void gemm512(
    const unsigned short* __restrict__ A,
    const unsigned short* __restrict__ BT,
    const float* __restrict__ bias,
    unsigned short* __restrict__ dq,
    unsigned short* __restrict__ dkv,
    int M, int N, int K)
{
    __shared__ unsigned short As[2][16384];  // 2 x (256 x 64)
    __shared__ unsigned short Bs[2][8192];   // 2 x (128 x 64)
    const int t = threadIdx.x;
    const int wave = t >> 6, lane = t & 63;
    const int ln = lane & 15, lq = lane >> 4;
    const int wm = (wave >> 1) * 64, wn = (wave & 1) * 64;

    // bijective XCD remap (576 = 8*72 exact)
    int bid0 = blockIdx.y * gridDim.x + blockIdx.x;
    int bid = (bid0 & 7) * 72 + (bid0 >> 3);
    int by = bid / 18, bx = bid - by * 18;
    const int bm = by * 256, bn = bx * 128;

    f32x4_t acc[4][4];
    for (int i = 0; i < 4; i++)
        for (int j = 0; j < 4; j++) acc[i][j] = (f32x4_t)(0.f);

    const int rl8 = lane >> 3;
    const int swz = ((lane & 7) ^ rl8) * 8;
    const unsigned short* Ap = A + (size_t)(bm + wave * 32 + rl8) * K + swz;
    const unsigned short* Bp = BT + (size_t)(bn + wave * 16 + rl8) * K + swz;

    const int e0 = (lq ^ (ln & 7)) * 8;
    const int e1 = e0 ^ 32;

    auto compute = [&](const unsigned short* Ac, const unsigned short* Bc) {
        bf16x8_t af0[4], af1[4], bf0[4], bf1[4];
#pragma unroll
        for (int mt = 0; mt < 4; mt++) {
            af0[mt] = *(const bf16x8_t*)&Ac[(wm + mt * 16 + ln) * 64 + e0];
            af1[mt] = *(const bf16x8_t*)&Ac[(wm + mt * 16 + ln) * 64 + e1];
        }
#pragma unroll
        for (int nt = 0; nt < 4; nt++) {
            bf0[nt] = *(const bf16x8_t*)&Bc[(wn + nt * 16 + ln) * 64 + e0];
            bf1[nt] = *(const bf16x8_t*)&Bc[(wn + nt * 16 + ln) * 64 + e1];
        }
        __builtin_amdgcn_s_setprio(1);
#pragma unroll
        for (int mt = 0; mt < 4; mt++)
#pragma unroll
            for (int nt = 0; nt < 4; nt++)
                acc[mt][nt] = __builtin_amdgcn_mfma_f32_16x16x32_bf16(
                    af0[mt], bf0[nt], acc[mt][nt], 0, 0, 0);
#pragma unroll
        for (int mt = 0; mt < 4; mt++)
#pragma unroll
            for (int nt = 0; nt < 4; nt++)
                acc[mt][nt] = __builtin_amdgcn_mfma_f32_16x16x32_bf16(
                    af1[mt], bf1[nt], acc[mt][nt], 0, 0, 0);
        __builtin_amdgcn_s_setprio(0);
    };

    // prologue: stage k-tile 0 into buf 0
    for (int i = 0; i < 4; i++)
        gl16(Ap + (size_t)(i * 8) * K, &As[0][wave * 2048 + i * 512]);
    for (int i = 0; i < 2; i++)
        gl16(Bp + (size_t)(i * 8) * K, &Bs[0][wave * 1024 + i * 512]);
    __syncthreads();   // implicit vmcnt(0): buf0 ready

    int cur = 0;
    for (int k0 = 0; k0 < K - 64; k0 += 64) {
        const int nb = cur ^ 1;
        // prefetch next k-tile; its latency hides under this step's MFMA
        for (int i = 0; i < 4; i++)
            gl16(Ap + (size_t)(i * 8) * K + k0 + 64, &As[nb][wave * 2048 + i * 512]);
        for (int i = 0; i < 2; i++)
            gl16(Bp + (size_t)(i * 8) * K + k0 + 64, &Bs[nb][wave * 1024 + i * 512]);
        compute(As[cur], Bs[cur]);
        __syncthreads();   // drains prefetch (vmcnt) + own ds_reads (lgkm)
        cur = nb;
    }
    compute(As[cur], Bs[cur]);   // last k-tile, no prefetch

    const float QSCALE = 0.125f * 1.44269504088896340736f;
    const int s = bn / 768;          // block-uniform: 768 % 128 == 0
    for (int nt = 0; nt < 4; nt++) {
        int c = bn + wn + nt * 16 + ln;
        int rem = c - s * 768;
        int h = rem >> 6, d = rem & 63;
        float bv = bias[c];
        for (int mt = 0; mt < 4; mt++) {
            for (int r = 0; r < 4; r++) {
                int row = bm + wm + mt * 16 + lq * 4 + r;
                float val = acc[mt][nt][r] + bv;
                if (s == 0) {
                    dq[(size_t)row * 768 + rem] = f2b(val * QSCALE);
                } else {
                    int bb = row >> 10, tt = row & 1023;
                    dkv[(size_t)(s - 1) * QSZ +
                        (((size_t)(bb * 12 + h) * 1024 + tt) << 6) + d] = f2b(val);
                }
            }
        }
    }
}

// ---- 128x128 bf16 GEMM, BK=64, XOR-swizzled, double-buffered 2-phase
// pipeline (same r11 transform as gemm512); out-proj: 384 blocks. ----
__global__ __launch_bounds__(256) void gemm_bt(
    const unsigned short* __restrict__ A,
    const unsigned short* __restrict__ BT,
    const float* __restrict__ bias,
    float* __restrict__ df,
    int M, int N, int K)
{
    __shared__ unsigned short As[2][8192];   // 2 x (128 x 64)
    __shared__ unsigned short Bs[2][8192];
    const int t = threadIdx.x;
    const int wave = t >> 6, lane = t & 63;
    const int ln = lane & 15, lq = lane >> 4;
    const int wm = (wave >> 1) * 64, wn = (wave & 1) * 64;
    const int bm = blockIdx.y * 128, bn = blockIdx.x * 128;

    f32x4_t acc[4][4];
    for (int i = 0; i < 4; i++)
        for (int j = 0; j < 4; j++) acc[i][j] = (f32x4_t)(0.f);

    const int rl8 = lane >> 3;
    const int swz = ((lane & 7) ^ rl8) * 8;
    const unsigned short* Ap = A + (size_t)(bm + wave * 32 + rl8) * K + swz;
    const unsigned short* Bp = BT + (size_t)(bn + wave * 32 + rl8) * K + swz;

    const int e0 = (lq ^ (ln & 7)) * 8;
    const int e1 = e0 ^ 32;

    auto compute = [&](const unsigned short* Ac, const unsigned short* Bc) {
        bf16x8_t af0[4], af1[4], bf0[4], bf1[4];
#pragma unroll
        for (int mt = 0; mt < 4; mt++) {
            af0[mt] = *(const bf16x8_t*)&Ac[(wm + mt * 16 + ln) * 64 + e0];
            af1[mt] = *(const bf16x8_t*)&Ac[(wm + mt * 16 + ln) * 64 + e1];
        }
#pragma unroll
        for (int nt = 0; nt < 4; nt++) {
            bf0[nt] = *(const bf16x8_t*)&Bc[(wn + nt * 16 + ln) * 64 + e0];
            bf1[nt] = *(const bf16x8_t*)&Bc[(wn + nt * 16 + ln) * 64 + e1];
        }
        __builtin_amdgcn_s_setprio(1);
#pragma unroll
        for (int mt = 0; mt < 4; mt++)
#pragma unroll
            for (int nt = 0; nt < 4; nt++)
                acc[mt][nt] = __builtin_amdgcn_mfma_f32_16x16x32_bf16(
                    af0[mt], bf0[nt], acc[mt][nt], 0, 0, 0);
#pragma unroll
        for (int mt = 0; mt < 4; mt++)
#pragma unroll
            for (int nt = 0; nt < 4; nt++)
                acc[mt][nt] = __builtin_amdgcn_mfma_f32_16x16x32_bf16(
                    af1[mt], bf1[nt], acc[mt][nt], 0, 0, 0);
        __builtin_amdgcn_s_setprio(0);
    };

    // prologue: stage k-tile 0 into buf 0
    for (int i = 0; i < 4; i++) {
        gl16(Ap + (size_t)(i * 8) * K, &As[0][wave * 2048 + i * 512]);
        gl16(Bp + (size_t)(i * 8) * K, &Bs[0][wave * 2048 + i * 512]);
    }
    __syncthreads();

    int cur = 0;
    for (int k0 = 0; k0 < K - 64; k0 += 64) {
        const int nb = cur ^ 1;
        for (int i = 0; i < 4; i++) {
            gl16(Ap + (size_t)(i * 8) * K + k0 + 64, &As[nb][wave * 2048 + i * 512]);
            gl16(Bp + (size_t)(i * 8) * K + k0 + 64, &Bs[nb][wave * 2048 + i * 512]);
        }
        compute(As[cur], Bs[cur]);
        __syncthreads();
        cur = nb;
    }
    compute(As[cur], Bs[cur]);

    for (int nt = 0; nt < 4; nt++) {
        int c = bn + wn + nt * 16 + ln;
        float bv = bias[c];
        for (int mt = 0; mt < 4; mt++)
            for (int r = 0; r < 4; r++) {
                int row = bm + wm + mt * 16 + lq * 4 + r;
                df[(size_t)row * N + c] = acc[mt][nt][r] + bv;
            }
    }
}

// ---- flash attention: 512 threads, 128 q-rows/block (8 waves x 16 q-rows),
// 128-key kt steps, unnormalized exp2 (scale folded into q), XOR-swizzled LDS. ----
__global__ __launch_bounds__(512) void attn_kernel(
    unsigned short* __restrict__ qio,           // [B,T,768] bf16, in/out (q pre-scaled)
    const unsigned short* __restrict__ k_ws,    // [B,H,T,D] bf16
    const unsigned short* __restrict__ vT_ws,   // [B,H,D,T] bf16 (transposed)
    const unsigned short* __restrict__ mem_k,   // [H,M,D]   bf16
    const unsigned short* __restrict__ mem_v)   // [H,D,M]   bf16
{
    __shared__ unsigned short Qs[8192];   // 128x64; aliased as Ps after frag hoist
    __shared__ unsigned short Ks[8192];   // two 64-key tiles
    __shared__ unsigned short Vs[8192];   // two 64-key tiles (rows = d)
    unsigned short* Ps = Qs;

    const int t = threadIdx.x;
    const int wave = t >> 6, lane = t & 63;
    const int ln = lane & 15, lq = lane >> 4;
    const int rl = lane >> 3;
    const int cl = ((lane & 7) ^ rl) * 8;

    // XCD swizzle: 8 q-tiles of one (b,h) land on one XCD
    int bid = blockIdx.x;
    int xcd = bid & 7, rest = bid >> 3;        // rest 0..95
    int bh = xcd * 12 + (rest >> 3);           // 0..95 == b*NH + h
    int qt = rest & 7;                         // 0..7 (128-row q tiles)
    int b = bh / 12, h = bh - b * 12;

    unsigned short* qp = qio + ((size_t)(b * TT + qt * 128)) * 768 + h * 64;
    const unsigned short* kp = k_ws + (size_t)bh * TT * 64;
    const unsigned short* vp = vT_ws + ((size_t)bh << 16);
    const unsigned short* mkp = mem_k + h * 4096;
    const unsigned short* mvp = mem_v + h * 4096;

    // stage Q (2 slabs per wave), hoist this wave's A-fragments (16 q-rows)
    {
        const unsigned short* qg = qp + (size_t)(wave * 16 + rl) * 768 + cl;
        gl16(qg, &Qs[wave * 1024]);
        gl16(qg + (size_t)8 * 768, &Qs[wave * 1024 + 512]);
    }
    __syncthreads();
    const int e0 = (lq ^ (ln & 7)) * 8;
    const int e1 = ((lq ^ (ln & 7)) ^ 4) * 8;
    bf16x8_t aq0 = *(bf16x8_t*)&Qs[(wave * 16 + ln) * 64 + e0];
    bf16x8_t aq1 = *(bf16x8_t*)&Qs[(wave * 16 + ln) * 64 + e1];

    // staging bases: K slabs s=w*2+i (keys s*8..+8); V slabs: half=s>>3, d-rows (s&7)*8..+8
    const unsigned short* kg = kp + (wave * 16 + rl) * 64 + cl;
    const unsigned short* vg = vp + (size_t)((wave & 3) * 16 + rl) * 1024 + (wave >> 2) * 64 + cl;

    const int hi3 = ln >> 3, lo3 = ln & 7;
    const int pm = (lq & 1) << 2;
    const int pw0 = (wave * 16 + lq * 4) * 64 + lo3;

    float lsum[4] = {0.f, 0.f, 0.f, 0.f};
    f32x4_t accO[4];
    for (int nt = 0; nt < 4; nt++) accO[nt] = (f32x4_t)(0.f);

    for (int kt = 0; kt < 8; kt++) {
        __syncthreads();
        gl16(kg + kt * 8192,        &Ks[wave * 1024]);
        gl16(kg + kt * 8192 + 512,  &Ks[wave * 1024 + 512]);
        gl16(vg + kt * 128,                 &Vs[wave * 1024]);
        gl16(vg + (size_t)8 * 1024 + kt * 128, &Vs[wave * 1024 + 512]);
        __syncthreads();

        for (int half = 0; half < 2; half++) {
            const unsigned short* Kh = &Ks[half * 4096];
            const unsigned short* Vh = &Vs[half * 4096];
            f32x4_t s[4];
            for (int nt = 0; nt < 4; nt++) s[nt] = (f32x4_t)(0.f);
            for (int nt = 0; nt < 4; nt++)
                s[nt] = __builtin_amdgcn_mfma_f32_16x16x32_bf16(
                    aq0, *(bf16x8_t*)&Kh[(nt * 16 + ln) * 64 + e0], s[nt], 0, 0, 0);
            for (int nt = 0; nt < 4; nt++)
                s[nt] = __builtin_amdgcn_mfma_f32_16x16x32_bf16(
                    aq1, *(bf16x8_t*)&Kh[(nt * 16 + ln) * 64 + e1], s[nt], 0, 0, 0);

            for (int nt = 0; nt < 4; nt++) {
                for (int r = 0; r < 4; r++) {
                    float p = __builtin_amdgcn_exp2f(s[nt][r]);
                    lsum[r] += p;
                    int chp = (nt * 2 + hi3) ^ pm ^ r;
                    Ps[pw0 + r * 64 + chp * 8] = f2b_ru(p);
                }
            }
            // Ps slab is wave-private: no barrier needed
            bf16x8_t a0 = *(bf16x8_t*)&Ps[(wave * 16 + ln) * 64 + e0];
            bf16x8_t a1 = *(bf16x8_t*)&Ps[(wave * 16 + ln) * 64 + e1];
            for (int nt = 0; nt < 4; nt++) {
                accO[nt] = __builtin_amdgcn_mfma_f32_16x16x32_bf16(
                    a0, *(bf16x8_t*)&Vh[(nt * 16 + ln) * 64 + e0], accO[nt], 0, 0, 0);
                accO[nt] = __builtin_amdgcn_mfma_f32_16x16x32_bf16(
                    a1, *(bf16x8_t*)&Vh[(nt * 16 + ln) * 64 + e1], accO[nt], 0, 0, 0);
            }
        }
    }

    // memory attention: 64 projected keys (each wave stages 1 slab of K and V)
    __syncthreads();
    gl16(mkp + (wave * 8 + rl) * 64 + cl, &Ks[wave * 512]);
    gl16(mvp + (wave * 8 + rl) * 64 + cl, &Vs[wave * 512]);
    __syncthreads();

    f32x4_t s2[4];
    for (int nt = 0; nt < 4; nt++) s2[nt] = (f32x4_t)(0.f);
    for (int nt = 0; nt < 4; nt++)
        s2[nt] = __builtin_amdgcn_mfma_f32_16x16x32_bf16(
            aq0, *(bf16x8_t*)&Ks[(nt * 16 + ln) * 64 + e0], s2[nt], 0, 0, 0);
    for (int nt = 0; nt < 4; nt++)
        s2[nt] = __builtin_amdgcn_mfma_f32_16x16x32_bf16(
            aq1, *(bf16x8_t*)&Ks[(nt * 16 + ln) * 64 + e1], s2[nt], 0, 0, 0);

    float l2[4] = {0.f, 0.f, 0.f, 0.f};
    for (int nt = 0; nt < 4; nt++) {
        for (int r = 0; r < 4; r++) {
            float p = __builtin_amdgcn_exp2f(s2[nt][r]);
            l2[r] += p;
            int chp = (nt * 2 + hi3) ^ pm ^ r;
            Ps[pw0 + r * 64 + chp * 8] = f2b_ru(p);
        }
    }
    f32x4_t accM[4];
    for (int nt = 0; nt < 4; nt++) accM[nt] = (f32x4_t)(0.f);
    {
        bf16x8_t a0 = *(bf16x8_t*)&Ps[(wave * 16 + ln) * 64 + e0];
        bf16x8_t a1 = *(bf16x8_t*)&Ps[(wave * 16 + ln) * 64 + e1];
        for (int nt = 0; nt < 4; nt++) {
            accM[nt] = __builtin_amdgcn_mfma_f32_16x16x32_bf16(
                a0, *(bf16x8_t*)&Vs[(nt * 16 + ln) * 64 + e0], accM[nt], 0, 0, 0);
            accM[nt] = __builtin_amdgcn_mfma_f32_16x16x32_bf16(
                a1, *(bf16x8_t*)&Vs[(nt * 16 + ln) * 64 + e1], accM[nt], 0, 0, 0);
        }
    }

    float inv[4], inv2[4];
    for (int r = 0; r < 4; r++) {
        float a = lsum[r], c = l2[r];
        a += __shfl_xor(a, 1); a += __shfl_xor(a, 2);
        a += __shfl_xor(a, 4); a += __shfl_xor(a, 8);
        c += __shfl_xor(c, 1); c += __shfl_xor(c, 2);
        c += __shfl_xor(c, 4); c += __shfl_xor(c, 8);
        inv[r] = 1.f / a;
        inv2[r] = 1.f / c;
    }

    for (int nt = 0; nt < 4; nt++) {
        for (int r = 0; r < 4; r++) {
            int lrow = wave * 16 + lq * 4 + r;
            int lcol = nt * 16 + ln;
            float val = accO[nt][r] * inv[r] + accM[nt][r] * inv2[r];
            qp[(size_t)lrow * 768 + lcol] = f2b(val);
        }
    }
}

// ---------------- host ----------------
extern "C" void kernel_launch(void* const* d_in, const int* in_sizes, int n_in,
                              void* d_out, int out_size, void* d_ws, size_t ws_size,
                              hipStream_t stream) {
    const float* x      = (const float*)d_in[0];
    const float* w_qkv  = (const float*)d_in[1];
    const float* b_qkv  = (const float*)d_in[2];
    const float* w_out  = (const float*)d_in[3];
    const float* b_out  = (const float*)d_in[4];
    const float* w_mem  = (const float*)d_in[5];
    const float* b_mem  = (const float*)d_in[6];
    const float* memory = (const float*)d_in[7];

    unsigned short* ws = (unsigned short*)d_ws;
    unsigned short* q_ws   = ws;                         // [B,T,C] bf16; attn in-place
    unsigned short* k_ws   = ws + (size_t)QSZ;           // [B,H,T,D]; v at +QSZ
    unsigned short* woutT  = ws + 3 * (size_t)QSZ;       // [768][768] bf16 (N x K)
    unsigned short* mem_k  = woutT + (size_t)EMBED * EMBED;
    unsigned short* mem_v  = mem_k + (size_t)NH * MEMN * HD;

    unsigned short* xb    = (unsigned short*)d_out;      // [8192][768] bf16
    unsigned short* wqkvT = xb + (size_t)QSZ;            // [2304][768] bf16
    unsigned short* vT    = (unsigned short*)d_out;      // [B,H,D,T] bf16

    // 1) fused prep (cvt + 2 tcvt + memproj)
    prep_kernel<<<PREP_TOTAL, 256, 0, stream>>>(
        x, w_qkv, w_out, memory, w_mem, b_mem, xb, wqkvT, woutT, mem_k, mem_v);

    // 2) QKV projection (512-thread 256x128 tiles): q -> q_ws; k,v -> [B,H,T,D]
    gemm512<<<dim3(QKV_N / 128, ROWS / 256), 512, 0, stream>>>(
        xb, wqkvT, b_qkv, q_ws, k_ws, ROWS, QKV_N, EMBED);

    // 3) transpose v -> vT [B,H,D,T]
    vtrans_kernel<<<dim3(TT / 64, BB * NH), 256, 0, stream>>>(k_ws + (size_t)QSZ, vT);

    // 4) attention (local flash + memory), in-place over q_ws; 768 blocks x 512 thr
    attn_kernel<<<8 * NH * BB, 512, 0, stream>>>(q_ws, k_ws, vT, mem_k, mem_v);

    // 5) output projection: q_ws(bf16) @ w_out + b_out -> d_out fp32
    gemm_bt<<<dim3(EMBED / 128, ROWS / 128), 256, 0, stream>>>(
        q_ws, woutT, b_out, (float*)d_out, ROWS, EMBED, EMBED);
}

// Round 2
// 246.486 us; speedup vs baseline: 1.0189x; 1.0189x over previous
//
#include <hip/hip_runtime.h>

#define EMBED 768
#define NH 12
#define HD 64
#define MEMN 64
#define BB 8
#define TT 1024
#define ROWS 8192
#define QKV_N 2304
#define QSZ 6291456           // B*T*C = B*NH*TT*HD (elements)

typedef short bf16x8_t __attribute__((ext_vector_type(8)));
typedef float f32x4_t __attribute__((ext_vector_type(4)));

__device__ __forceinline__ unsigned short f2b(float f){
    union { float f; unsigned int i; } v; v.f = f;
    unsigned int x = v.i;
    unsigned int r = x + 0x7fffu + ((x >> 16) & 1u);
    return (unsigned short)(r >> 16);
}
// round-half-up convert for non-negative values (softmax p)
__device__ __forceinline__ unsigned short f2b_ru(float f){
    union { float f; unsigned int i; } v; v.f = f;
    return (unsigned short)((v.i + 0x8000u) >> 16);
}

// async global->LDS, 16B per lane; lds base must be wave-uniform (lane*16 implicit)
__device__ __forceinline__ void gl16(const unsigned short* g, unsigned short* l){
    __builtin_amdgcn_global_load_lds(
        (const __attribute__((address_space(1))) void*)g,
        (__attribute__((address_space(3))) void*)l,
        16, 0, 0);
}

#define SCHED_FENCE() __builtin_amdgcn_sched_barrier(0)

// ---- fused prep: x cvt + w_qkv tcvt + w_out tcvt + memproj (one graph node) ----
#define PREP_CVT   3072
#define PREP_TQKV  4800
#define PREP_TOUT  5376
#define PREP_TOTAL 5388

__global__ __launch_bounds__(256) void prep_kernel(
    const float* __restrict__ x,
    const float* __restrict__ w_qkv,
    const float* __restrict__ w_out,
    const float* __restrict__ memory,
    const float* __restrict__ w_mem,
    const float* __restrict__ b_mem,
    unsigned short* __restrict__ xb,
    unsigned short* __restrict__ wqkvT,
    unsigned short* __restrict__ woutT,
    unsigned short* __restrict__ mem_k,
    unsigned short* __restrict__ mem_v)
{
    __shared__ unsigned short pool[5120];
    const int bid = blockIdx.x;
    const int t = threadIdx.x;

    if (bid < PREP_CVT) {
        int i = bid * 2048 + t * 8;
        float4 f0 = *(const float4*)&x[i];
        float4 f1 = *(const float4*)&x[i + 4];
        union { bf16x8_t v; unsigned short s[8]; } u;
        u.s[0] = f2b(f0.x); u.s[1] = f2b(f0.y); u.s[2] = f2b(f0.z); u.s[3] = f2b(f0.w);
        u.s[4] = f2b(f1.x); u.s[5] = f2b(f1.y); u.s[6] = f2b(f1.z); u.s[7] = f2b(f1.w);
        *(bf16x8_t*)&xb[i] = u.v;
    } else if (bid < PREP_TOUT) {
        const float* in; unsigned short* out; int R, C, loc;
        if (bid < PREP_TQKV) { in = w_qkv; out = wqkvT; R = EMBED; C = QKV_N; loc = bid - PREP_CVT; }
        else                 { in = w_out; out = woutT; R = EMBED; C = EMBED; loc = bid - PREP_TQKV; }
        int nbc = C / 32;
        int bc = (loc % nbc) * 32, br = (loc / nbc) * 32;
        unsigned short (*tile)[33] = (unsigned short(*)[33])pool;
        int lr = t >> 5, lc = t & 31;
        for (int i = 0; i < 4; i++) {
            int r = lr + i * 8;
            tile[r][lc] = f2b(in[(size_t)(br + r) * C + bc + lc]);
        }
        __syncthreads();
        for (int i = 0; i < 4; i++) {
            int r = lr + i * 8;
            out[(size_t)(bc + r) * R + br + lc] = tile[lc][r];
        }
    } else {
        unsigned short (*As)[40] = (unsigned short(*)[40])pool;
        unsigned short (*Bs)[40] = (unsigned short(*)[40])(pool + 2560);
        int wave = t >> 6, lane = t & 63;
        int ln = lane & 15, lq = lane >> 4;
        int bn = (bid - PREP_TOUT) * 64;
        const int K = EMBED, N = EMBED;

        f32x4_t acc[4];
        for (int i = 0; i < 4; i++) acc[i] = (f32x4_t)(0.f);
        int sm = t >> 2, sk = (t & 3) * 8;
        int bk = t >> 3, bn8 = (t & 7) * 8;

        for (int k0 = 0; k0 < K; k0 += 32) {
            __syncthreads();
            {
                float4 f0 = *(const float4*)&memory[(size_t)sm * K + k0 + sk];
                float4 f1 = *(const float4*)&memory[(size_t)sm * K + k0 + sk + 4];
                unsigned short* ap = &As[sm][sk];
                ap[0] = f2b(f0.x); ap[1] = f2b(f0.y); ap[2] = f2b(f0.z); ap[3] = f2b(f0.w);
                ap[4] = f2b(f1.x); ap[5] = f2b(f1.y); ap[6] = f2b(f1.z); ap[7] = f2b(f1.w);
            }
            {
                float4 g0 = *(const float4*)&w_mem[(size_t)(k0 + bk) * N + bn + bn8];
                float4 g1 = *(const float4*)&w_mem[(size_t)(k0 + bk) * N + bn + bn8 + 4];
                Bs[bn8 + 0][bk] = f2b(g0.x); Bs[bn8 + 1][bk] = f2b(g0.y);
                Bs[bn8 + 2][bk] = f2b(g0.z); Bs[bn8 + 3][bk] = f2b(g0.w);
                Bs[bn8 + 4][bk] = f2b(g1.x); Bs[bn8 + 5][bk] = f2b(g1.y);
                Bs[bn8 + 6][bk] = f2b(g1.z); Bs[bn8 + 7][bk] = f2b(g1.w);
            }
            __syncthreads();
            bf16x8_t a = *(bf16x8_t*)&As[wave * 16 + ln][lq * 8];
            for (int nt = 0; nt < 4; nt++) {
                bf16x8_t bf = *(bf16x8_t*)&Bs[nt * 16 + ln][lq * 8];
                acc[nt] = __builtin_amdgcn_mfma_f32_16x16x32_bf16(a, bf, acc[nt], 0, 0, 0);
            }
        }
        for (int nt = 0; nt < 4; nt++) {
            int c = bn + nt * 16 + ln;
            float bv = b_mem[c];
            for (int r = 0; r < 4; r++) {
                int row = wave * 16 + lq * 4 + r;
                int h = c >> 6, d = c & 63;
                unsigned short o = f2b(acc[nt][r] + bv);
                mem_k[((h * 64 + row) << 6) + d] = o;   // [H,M,D]
                mem_v[((h * 64 + d) << 6) + row] = o;   // [H,D,M]
            }
        }
    }
}

// ---- bf16 [BH][T][D] -> [BH][D][T] transpose, coalesced both sides ----
__global__ __launch_bounds__(256) void vtrans_kernel(
    const unsigned short* __restrict__ in, unsigned short* __restrict__ out)
{
    __shared__ unsigned short tile[64][72];
    int t0 = blockIdx.x * 64;
    int bh = blockIdx.y;
    const unsigned short* ip = in + ((size_t)bh * TT + t0) * 64;
    unsigned short* op = out + ((size_t)bh * 64) * TT + t0;
    int t = threadIdx.x;
    for (int i = 0; i < 2; i++) {
        int idx = i * 256 + t;
        int r = idx >> 3, c8 = (idx & 7) * 8;
        *(bf16x8_t*)&tile[r][c8] = *(const bf16x8_t*)&ip[(size_t)r * 64 + c8];
    }
    __syncthreads();
    for (int i = 0; i < 2; i++) {
        int idx = i * 256 + t;
        int d = idx >> 3, tc8 = (idx & 7) * 8;
        union { bf16x8_t v; unsigned short s[8]; } u;
        for (int j = 0; j < 8; j++) u.s[j] = tile[tc8 + j][d];
        *(bf16x8_t*)&op[(size_t)d * TT + tc8] = u.v;
    }
}

// ---- 256x128 bf16 GEMM, 512 threads (8 waves x 64x64 quadrant), BK=64,
// XOR-swizzled LDS, double-buffered.
// r12: 2-tile-deep counted-vmcnt pipeline (T3+T4). Tile t's 6 gl16 loads are
// issued during iter t-2 and verified by s_waitcnt vmcnt(6) at the end of iter
// t-1 (never vmcnt(0) in the main loop) -> every load has ~2 compute phases
// (~800-1000 cyc) of latency cover. Raw s_barrier carries NO implicit drain;
// sched_barrier(0) fences pin issue/wait/read order (guide rule #18).
// r11 post-mortem: dbuf with __syncthreads (vmcnt(0) drain each step) at
// 1 blk/CU lost the inter-block TLP of the 48KB version and regressed 60->68us.
// XCD swizzle (kept from r11): fetch 64->42 MB measured. ----
__global__ __launch_bounds__(512) void gemm512(
    const unsigned short* __restrict__ A,
    const unsigned short* __restrict__ BT,
    const float* __restrict__ bias,
    unsigned short* __restrict__ dq,
    unsigned short* __restrict__ dkv,
    int M, int N, int K)   // K == 768 always (literal used for strides)
{
    __shared__ unsigned short As[2][16384];  // 2 x (256 x 64)
    __shared__ unsigned short Bs[2][8192];   // 2 x (128 x 64)
    const int t = threadIdx.x;
    const int wave = t >> 6, lane = t & 63;
    const int ln = lane & 15, lq = lane >> 4;
    const int wm = (wave >> 1) * 64, wn = (wave & 1) * 64;

    // bijective XCD remap (576 = 8*72 exact)
    int bid0 = blockIdx.y * gridDim.x + blockIdx.x;
    int bid = (bid0 & 7) * 72 + (bid0 >> 3);
    int by = bid / 18, bx = bid - by * 18;
    const int bm = by * 256, bn = bx * 128;

    f32x4_t acc[4][4];
    for (int i = 0; i < 4; i++)
        for (int j = 0; j < 4; j++) acc[i][j] = (f32x4_t)(0.f);

    const int rl8 = lane >> 3;
    const int swz = ((lane & 7) ^ rl8) * 8;
    const unsigned short* Ap = A + (size_t)(bm + wave * 32 + rl8) * 768 + swz;
    const unsigned short* Bp = BT + (size_t)(bn + wave * 16 + rl8) * 768 + swz;

    const int e0 = (lq ^ (ln & 7)) * 8;
    const int e1 = e0 ^ 32;

    auto stage = [&](int buf, int k0) {
#pragma unroll
        for (int i = 0; i < 4; i++)
            gl16(Ap + (size_t)(i * 8) * 768 + k0, &As[buf][wave * 2048 + i * 512]);
#pragma unroll
        for (int i = 0; i < 2; i++)
            gl16(Bp + (size_t)(i * 8) * 768 + k0, &Bs[buf][wave * 1024 + i * 512]);
    };

    auto compute = [&](const unsigned short* Ac, const unsigned short* Bc) {
        bf16x8_t af0[4], af1[4], bf0[4], bf1[4];
#pragma unroll
        for (int mt = 0; mt < 4; mt++) {
            af0[mt] = *(const bf16x8_t*)&Ac[(wm + mt * 16 + ln) * 64 + e0];
            af1[mt] = *(const bf16x8_t*)&Ac[(wm + mt * 16 + ln) * 64 + e1];
        }
#pragma unroll
        for (int nt = 0; nt < 4; nt++) {
            bf0[nt] = *(const bf16x8_t*)&Bc[(wn + nt * 16 + ln) * 64 + e0];
            bf1[nt] = *(const bf16x8_t*)&Bc[(wn + nt * 16 + ln) * 64 + e1];
        }
        __builtin_amdgcn_s_setprio(1);
#pragma unroll
        for (int mt = 0; mt < 4; mt++)
#pragma unroll
            for (int nt = 0; nt < 4; nt++)
                acc[mt][nt] = __builtin_amdgcn_mfma_f32_16x16x32_bf16(
                    af0[mt], bf0[nt], acc[mt][nt], 0, 0, 0);
#pragma unroll
        for (int mt = 0; mt < 4; mt++)
#pragma unroll
            for (int nt = 0; nt < 4; nt++)
                acc[mt][nt] = __builtin_amdgcn_mfma_f32_16x16x32_bf16(
                    af1[mt], bf1[nt], acc[mt][nt], 0, 0, 0);
        __builtin_amdgcn_s_setprio(0);
    };

    // prologue: tiles 0 and 1 in flight (12 loads), wait tile 0 only
    stage(0, 0);
    stage(1, 64);
    SCHED_FENCE();
    asm volatile("s_waitcnt vmcnt(6)" ::: "memory");
    SCHED_FENCE();
    __builtin_amdgcn_s_barrier();
    SCHED_FENCE();

    // main loop: 12 K-tiles (K=768, BK=64); iters 0..9 pipelined
#pragma unroll 2
    for (int tt = 0; tt < 10; ++tt) {
        const int cur = tt & 1;
        compute(&As[cur][0], &Bs[cur][0]);
        SCHED_FENCE();
        __builtin_amdgcn_s_barrier();          // all waves done reading buf cur
        SCHED_FENCE();
        stage(cur, (tt + 2) * 64);             // tile tt+2 -> buf cur
        SCHED_FENCE();
        asm volatile("s_waitcnt vmcnt(6)" ::: "memory");  // tile tt+1 landed
        SCHED_FENCE();
        __builtin_amdgcn_s_barrier();          // tile tt+1 visible to all
        SCHED_FENCE();
    }
    // tail: tile 10 (buf0), then tile 11 (buf1)
    compute(&As[0][0], &Bs[0][0]);
    SCHED_FENCE();
    asm volatile("s_waitcnt vmcnt(0)" ::: "memory");
    SCHED_FENCE();
    __builtin_amdgcn_s_barrier();
    SCHED_FENCE();
    compute(&As[1][0], &Bs[1][0]);

    const float QSCALE = 0.125f * 1.44269504088896340736f;
    const int s = bn / 768;          // block-uniform: 768 % 128 == 0
    for (int nt = 0; nt < 4; nt++) {
        int c = bn + wn + nt * 16 + ln;
        int rem = c - s * 768;
        int h = rem >> 6, d = rem & 63;
        float bv = bias[c];
        for (int mt = 0; mt < 4; mt++) {
            for (int r = 0; r < 4; r++) {
                int row = bm + wm + mt * 16 + lq * 4 + r;
                float val = acc[mt][nt][r] + bv;
                if (s == 0) {
                    dq[(size_t)row * 768 + rem] = f2b(val * QSCALE);
                } else {
                    int bb = row >> 10, tt2 = row & 1023;
                    dkv[(size_t)(s - 1) * QSZ +
                        (((size_t)(bb * 12 + h) * 1024 + tt2) << 6) + d] = f2b(val);
                }
            }
        }
    }
}

// ---- 128x128 bf16 GEMM, BK=64, XOR-swizzled, double-buffered,
// same r12 counted-vmcnt 2-deep pipeline (8 loads/tile -> vmcnt(8));
// 64 KB LDS keeps 2 blocks/CU. out-proj: 384 blocks. ----
__global__ __launch_bounds__(256) void gemm_bt(
    const unsigned short* __restrict__ A,
    const unsigned short* __restrict__ BT,
    const float* __restrict__ bias,
    float* __restrict__ df,
    int M, int N, int K)   // K == 768 always
{
    __shared__ unsigned short As[2][8192];   // 2 x (128 x 64)
    __shared__ unsigned short Bs[2][8192];
    const int t = threadIdx.x;
    const int wave = t >> 6, lane = t & 63;
    const int ln = lane & 15, lq = lane >> 4;
    const int wm = (wave >> 1) * 64, wn = (wave & 1) * 64;
    const int bm = blockIdx.y * 128, bn = blockIdx.x * 128;

    f32x4_t acc[4][4];
    for (int i = 0; i < 4; i++)
        for (int j = 0; j < 4; j++) acc[i][j] = (f32x4_t)(0.f);

    const int rl8 = lane >> 3;
    const int swz = ((lane & 7) ^ rl8) * 8;
    const unsigned short* Ap = A + (size_t)(bm + wave * 32 + rl8) * 768 + swz;
    const unsigned short* Bp = BT + (size_t)(bn + wave * 32 + rl8) * 768 + swz;

    const int e0 = (lq ^ (ln & 7)) * 8;
    const int e1 = e0 ^ 32;

    auto stage = [&](int buf, int k0) {
#pragma unroll
        for (int i = 0; i < 4; i++) {
            gl16(Ap + (size_t)(i * 8) * 768 + k0, &As[buf][wave * 2048 + i * 512]);
            gl16(Bp + (size_t)(i * 8) * 768 + k0, &Bs[buf][wave * 2048 + i * 512]);
        }
    };

    auto compute = [&](const unsigned short* Ac, const unsigned short* Bc) {
        bf16x8_t af0[4], af1[4], bf0[4], bf1[4];
#pragma unroll
        for (int mt = 0; mt < 4; mt++) {
            af0[mt] = *(const bf16x8_t*)&Ac[(wm + mt * 16 + ln) * 64 + e0];
            af1[mt] = *(const bf16x8_t*)&Ac[(wm + mt * 16 + ln) * 64 + e1];
        }
#pragma unroll
        for (int nt = 0; nt < 4; nt++) {
            bf0[nt] = *(const bf16x8_t*)&Bc[(wn + nt * 16 + ln) * 64 + e0];
            bf1[nt] = *(const bf16x8_t*)&Bc[(wn + nt * 16 + ln) * 64 + e1];
        }
        __builtin_amdgcn_s_setprio(1);
#pragma unroll
        for (int mt = 0; mt < 4; mt++)
#pragma unroll
            for (int nt = 0; nt < 4; nt++)
                acc[mt][nt] = __builtin_amdgcn_mfma_f32_16x16x32_bf16(
                    af0[mt], bf0[nt], acc[mt][nt], 0, 0, 0);
#pragma unroll
        for (int mt = 0; mt < 4; mt++)
#pragma unroll
            for (int nt = 0; nt < 4; nt++)
                acc[mt][nt] = __builtin_amdgcn_mfma_f32_16x16x32_bf16(
                    af1[mt], bf1[nt], acc[mt][nt], 0, 0, 0);
        __builtin_amdgcn_s_setprio(0);
    };

    // prologue: tiles 0,1 in flight (16 loads), wait tile 0
    stage(0, 0);
    stage(1, 64);
    SCHED_FENCE();
    asm volatile("s_waitcnt vmcnt(8)" ::: "memory");
    SCHED_FENCE();
    __builtin_amdgcn_s_barrier();
    SCHED_FENCE();

#pragma unroll 2
    for (int tt = 0; tt < 10; ++tt) {
        const int cur = tt & 1;
        compute(&As[cur][0], &Bs[cur][0]);
        SCHED_FENCE();
        __builtin_amdgcn_s_barrier();
        SCHED_FENCE();
        stage(cur, (tt + 2) * 64);
        SCHED_FENCE();
        asm volatile("s_waitcnt vmcnt(8)" ::: "memory");
        SCHED_FENCE();
        __builtin_amdgcn_s_barrier();
        SCHED_FENCE();
    }
    compute(&As[0][0], &Bs[0][0]);
    SCHED_FENCE();
    asm volatile("s_waitcnt vmcnt(0)" ::: "memory");
    SCHED_FENCE();
    __builtin_amdgcn_s_barrier();
    SCHED_FENCE();
    compute(&As[1][0], &Bs[1][0]);

    for (int nt = 0; nt < 4; nt++) {
        int c = bn + wn + nt * 16 + ln;
        float bv = bias[c];
        for (int mt = 0; mt < 4; mt++)
            for (int r = 0; r < 4; r++) {
                int row = bm + wm + mt * 16 + lq * 4 + r;
                df[(size_t)row * N + c] = acc[mt][nt][r] + bv;
            }
    }
}

// ---- flash attention: 512 threads, 128 q-rows/block (8 waves x 16 q-rows),
// 128-key kt steps, unnormalized exp2 (scale folded into q), XOR-swizzled LDS. ----
__global__ __launch_bounds__(512) void attn_kernel(
    unsigned short* __restrict__ qio,           // [B,T,768] bf16, in/out (q pre-scaled)
    const unsigned short* __restrict__ k_ws,    // [B,H,T,D] bf16
    const unsigned short* __restrict__ vT_ws,   // [B,H,D,T] bf16 (transposed)
    const unsigned short* __restrict__ mem_k,   // [H,M,D]   bf16
    const unsigned short* __restrict__ mem_v)   // [H,D,M]   bf16
{
    __shared__ unsigned short Qs[8192];   // 128x64; aliased as Ps after frag hoist
    __shared__ unsigned short Ks[8192];   // two 64-key tiles
    __shared__ unsigned short Vs[8192];   // two 64-key tiles (rows = d)
    unsigned short* Ps = Qs;

    const int t = threadIdx.x;
    const int wave = t >> 6, lane = t & 63;
    const int ln = lane & 15, lq = lane >> 4;
    const int rl = lane >> 3;
    const int cl = ((lane & 7) ^ rl) * 8;

    // XCD swizzle: 8 q-tiles of one (b,h) land on one XCD
    int bid = blockIdx.x;
    int xcd = bid & 7, rest = bid >> 3;        // rest 0..95
    int bh = xcd * 12 + (rest >> 3);           // 0..95 == b*NH + h
    int qt = rest & 7;                         // 0..7 (128-row q tiles)
    int b = bh / 12, h = bh - b * 12;

    unsigned short* qp = qio + ((size_t)(b * TT + qt * 128)) * 768 + h * 64;
    const unsigned short* kp = k_ws + (size_t)bh * TT * 64;
    const unsigned short* vp = vT_ws + ((size_t)bh << 16);
    const unsigned short* mkp = mem_k + h * 4096;
    const unsigned short* mvp = mem_v + h * 4096;

    // stage Q (2 slabs per wave), hoist this wave's A-fragments (16 q-rows)
    {
        const unsigned short* qg = qp + (size_t)(wave * 16 + rl) * 768 + cl;
        gl16(qg, &Qs[wave * 1024]);
        gl16(qg + (size_t)8 * 768, &Qs[wave * 1024 + 512]);
    }
    __syncthreads();
    const int e0 = (lq ^ (ln & 7)) * 8;
    const int e1 = ((lq ^ (ln & 7)) ^ 4) * 8;
    bf16x8_t aq0 = *(bf16x8_t*)&Qs[(wave * 16 + ln) * 64 + e0];
    bf16x8_t aq1 = *(bf16x8_t*)&Qs[(wave * 16 + ln) * 64 + e1];

    // staging bases: K slabs s=w*2+i (keys s*8..+8); V slabs: half=s>>3, d-rows (s&7)*8..+8
    const unsigned short* kg = kp + (wave * 16 + rl) * 64 + cl;
    const unsigned short* vg = vp + (size_t)((wave & 3) * 16 + rl) * 1024 + (wave >> 2) * 64 + cl;

    const int hi3 = ln >> 3, lo3 = ln & 7;
    const int pm = (lq & 1) << 2;
    const int pw0 = (wave * 16 + lq * 4) * 64 + lo3;

    float lsum[4] = {0.f, 0.f, 0.f, 0.f};
    f32x4_t accO[4];
    for (int nt = 0; nt < 4; nt++) accO[nt] = (f32x4_t)(0.f);

    for (int kt = 0; kt < 8; kt++) {
        __syncthreads();
        gl16(kg + kt * 8192,        &Ks[wave * 1024]);
        gl16(kg + kt * 8192 + 512,  &Ks[wave * 1024 + 512]);
        gl16(vg + kt * 128,                 &Vs[wave * 1024]);
        gl16(vg + (size_t)8 * 1024 + kt * 128, &Vs[wave * 1024 + 512]);
        __syncthreads();

        for (int half = 0; half < 2; half++) {
            const unsigned short* Kh = &Ks[half * 4096];
            const unsigned short* Vh = &Vs[half * 4096];
            f32x4_t s[4];
            for (int nt = 0; nt < 4; nt++) s[nt] = (f32x4_t)(0.f);
            for (int nt = 0; nt < 4; nt++)
                s[nt] = __builtin_amdgcn_mfma_f32_16x16x32_bf16(
                    aq0, *(bf16x8_t*)&Kh[(nt * 16 + ln) * 64 + e0], s[nt], 0, 0, 0);
            for (int nt = 0; nt < 4; nt++)
                s[nt] = __builtin_amdgcn_mfma_f32_16x16x32_bf16(
                    aq1, *(bf16x8_t*)&Kh[(nt * 16 + ln) * 64 + e1], s[nt], 0, 0, 0);

            for (int nt = 0; nt < 4; nt++) {
                for (int r = 0; r < 4; r++) {
                    float p = __builtin_amdgcn_exp2f(s[nt][r]);
                    lsum[r] += p;
                    int chp = (nt * 2 + hi3) ^ pm ^ r;
                    Ps[pw0 + r * 64 + chp * 8] = f2b_ru(p);
                }
            }
            // Ps slab is wave-private: no barrier needed
            bf16x8_t a0 = *(bf16x8_t*)&Ps[(wave * 16 + ln) * 64 + e0];
            bf16x8_t a1 = *(bf16x8_t*)&Ps[(wave * 16 + ln) * 64 + e1];
            for (int nt = 0; nt < 4; nt++) {
                accO[nt] = __builtin_amdgcn_mfma_f32_16x16x32_bf16(
                    a0, *(bf16x8_t*)&Vh[(nt * 16 + ln) * 64 + e0], accO[nt], 0, 0, 0);
                accO[nt] = __builtin_amdgcn_mfma_f32_16x16x32_bf16(
                    a1, *(bf16x8_t*)&Vh[(nt * 16 + ln) * 64 + e1], accO[nt], 0, 0, 0);
            }
        }
    }

    // memory attention: 64 projected keys (each wave stages 1 slab of K and V)
    __syncthreads();
    gl16(mkp + (wave * 8 + rl) * 64 + cl, &Ks[wave * 512]);
    gl16(mvp + (wave * 8 + rl) * 64 + cl, &Vs[wave * 512]);
    __syncthreads();

    f32x4_t s2[4];
    for (int nt = 0; nt < 4; nt++) s2[nt] = (f32x4_t)(0.f);
    for (int nt = 0; nt < 4; nt++)
        s2[nt] = __builtin_amdgcn_mfma_f32_16x16x32_bf16(
            aq0, *(bf16x8_t*)&Ks[(nt * 16 + ln) * 64 + e0], s2[nt], 0, 0, 0);
    for (int nt = 0; nt < 4; nt++)
        s2[nt] = __builtin_amdgcn_mfma_f32_16x16x32_bf16(
            aq1, *(bf16x8_t*)&Ks[(nt * 16 + ln) * 64 + e1], s2[nt], 0, 0, 0);

    float l2[4] = {0.f, 0.f, 0.f, 0.f};
    for (int nt = 0; nt < 4; nt++) {
        for (int r = 0; r < 4; r++) {
            float p = __builtin_amdgcn_exp2f(s2[nt][r]);
            l2[r] += p;
            int chp = (nt * 2 + hi3) ^ pm ^ r;
            Ps[pw0 + r * 64 + chp * 8] = f2b_ru(p);
        }
    }
    f32x4_t accM[4];
    for (int nt = 0; nt < 4; nt++) accM[nt] = (f32x4_t)(0.f);
    {
        bf16x8_t a0 = *(bf16x8_t*)&Ps[(wave * 16 + ln) * 64 + e0];
        bf16x8_t a1 = *(bf16x8_t*)&Ps[(wave * 16 + ln) * 64 + e1];
        for (int nt = 0; nt < 4; nt++) {
            accM[nt] = __builtin_amdgcn_mfma_f32_16x16x32_bf16(
                a0, *(bf16x8_t*)&Vs[(nt * 16 + ln) * 64 + e0], accM[nt], 0, 0, 0);
            accM[nt] = __builtin_amdgcn_mfma_f32_16x16x32_bf16(
                a1, *(bf16x8_t*)&Vs[(nt * 16 + ln) * 64 + e1], accM[nt], 0, 0, 0);
        }
    }

    float inv[4], inv2[4];
    for (int r = 0; r < 4; r++) {
        float a = lsum[r], c = l2[r];
        a += __shfl_xor(a, 1); a += __shfl_xor(a, 2);
        a += __shfl_xor(a, 4); a += __shfl_xor(a, 8);
        c += __shfl_xor(c, 1); c += __shfl_xor(c, 2);
        c += __shfl_xor(c, 4); c += __shfl_xor(c, 8);
        inv[r] = 1.f / a;
        inv2[r] = 1.f / c;
    }

    for (int nt = 0; nt < 4; nt++) {
        for (int r = 0; r < 4; r++) {
            int lrow = wave * 16 + lq * 4 + r;
            int lcol = nt * 16 + ln;
            float val = accO[nt][r] * inv[r] + accM[nt][r] * inv2[r];
            qp[(size_t)lrow * 768 + lcol] = f2b(val);
        }
    }
}

// ---------------- host ----------------
extern "C" void kernel_launch(void* const* d_in, const int* in_sizes, int n_in,
                              void* d_out, int out_size, void* d_ws, size_t ws_size,
                              hipStream_t stream) {
    const float* x      = (const float*)d_in[0];
    const float* w_qkv  = (const float*)d_in[1];
    const float* b_qkv  = (const float*)d_in[2];
    const float* w_out  = (const float*)d_in[3];
    const float* b_out  = (const float*)d_in[4];
    const float* w_mem  = (const float*)d_in[5];
    const float* b_mem  = (const float*)d_in[6];
    const float* memory = (const float*)d_in[7];

    unsigned short* ws = (unsigned short*)d_ws;
    unsigned short* q_ws   = ws;                         // [B,T,C] bf16; attn in-place
    unsigned short* k_ws   = ws + (size_t)QSZ;           // [B,H,T,D]; v at +QSZ
    unsigned short* woutT  = ws + 3 * (size_t)QSZ;       // [768][768] bf16 (N x K)
    unsigned short* mem_k  = woutT + (size_t)EMBED * EMBED;
    unsigned short* mem_v  = mem_k + (size_t)NH * MEMN * HD;

    unsigned short* xb    = (unsigned short*)d_out;      // [8192][768] bf16
    unsigned short* wqkvT = xb + (size_t)QSZ;            // [2304][768] bf16
    unsigned short* vT    = (unsigned short*)d_out;      // [B,H,D,T] bf16

    // 1) fused prep (cvt + 2 tcvt + memproj)
    prep_kernel<<<PREP_TOTAL, 256, 0, stream>>>(
        x, w_qkv, w_out, memory, w_mem, b_mem, xb, wqkvT, woutT, mem_k, mem_v);

    // 2) QKV projection (512-thread 256x128 tiles): q -> q_ws; k,v -> [B,H,T,D]
    gemm512<<<dim3(QKV_N / 128, ROWS / 256), 512, 0, stream>>>(
        xb, wqkvT, b_qkv, q_ws, k_ws, ROWS, QKV_N, EMBED);

    // 3) transpose v -> vT [B,H,D,T]
    vtrans_kernel<<<dim3(TT / 64, BB * NH), 256, 0, stream>>>(k_ws + (size_t)QSZ, vT);

    // 4) attention (local flash + memory), in-place over q_ws; 768 blocks x 512 thr
    attn_kernel<<<8 * NH * BB, 512, 0, stream>>>(q_ws, k_ws, vT, mem_k, mem_v);

    // 5) output projection: q_ws(bf16) @ w_out + b_out -> d_out fp32
    gemm_bt<<<dim3(EMBED / 128, ROWS / 128), 256, 0, stream>>>(
        q_ws, woutT, b_out, (float*)d_out, ROWS, EMBED, EMBED);
}